// Round 11
// baseline (1196.669 us; speedup 1.0000x reference)
//
#include <hip/hip_runtime.h>
#include <stdint.h>

#define DEV static __device__ __forceinline__

typedef __attribute__((ext_vector_type(8))) __bf16 bf16x8;
typedef __attribute__((ext_vector_type(4))) float f32x4;
typedef unsigned short u16;
typedef unsigned int u32;

// ---------- scalar helpers ----------
DEV u16 f2b(float f) {                       // fp32 -> bf16 bits, RN-even
  u32 u = __float_as_uint(f);
  u32 r = (u + 0x7FFFu + ((u >> 16) & 1u)) >> 16;
  return (u16)r;
}

DEV void gload16(const u16* g, u16* l) {     // async global->LDS, 16B/lane
  __builtin_amdgcn_global_load_lds(
      (const __attribute__((address_space(1))) u32*)g,
      (__attribute__((address_space(3))) u32*)l, 16, 0, 0);
}

// ---------- W (K x N fp32, row-major) -> Wt (N x K bf16) ----------
__global__ __launch_bounds__(256) void wt_bf16(const float* __restrict__ W,
                                               u16* __restrict__ Wt, int K, int N) {
  __shared__ float t[32][33];
  int n0 = blockIdx.x * 32, k0 = blockIdx.y * 32;
  int tx = threadIdx.x & 31, ty = threadIdx.x >> 5;   // ty 0..7
#pragma unroll
  for (int i = 0; i < 32; i += 8)
    t[ty + i][tx] = W[(long)(k0 + ty + i) * N + n0 + tx];
  __syncthreads();
#pragma unroll
  for (int i = 0; i < 32; i += 8)
    Wt[(long)(n0 + ty + i) * K + k0 + tx] = f2b(t[tx][ty + i]);
}

// ---------- ada = silu(c) @ W_ada + b_ada  (8 x 6912) ----------
__global__ __launch_bounds__(512) void ada_gemm(const float* __restrict__ c,
                                                const float* __restrict__ W,
                                                const float* __restrict__ bias,
                                                float* __restrict__ ada) {
  __shared__ float sc[8 * 1152];
  int t = threadIdx.x;
  for (int i = t; i < 8 * 1152; i += 512) {
    float v = c[i];
    sc[i] = v / (1.f + __expf(-v));
  }
  __syncthreads();
  int n = blockIdx.x * 64 + (t & 63), b = t >> 6;
  const float* wp = W + n;
  const float* scp = sc + b * 1152;
  float acc = 0.f;
#pragma unroll 8
  for (int k = 0; k < 1152; ++k) acc = fmaf(scp[k], wp[(long)k * 6912], acc);
  ada[b * 6912 + n] = acc + bias[n];
}

// ---------- LayerNorm + modulate -> bf16 ----------
__global__ __launch_bounds__(256) void ln_mod(const float* __restrict__ X,
                                              const float* __restrict__ ada,
                                              int so, int co, u16* __restrict__ out) {
  int r = blockIdx.x, b = r >> 10, t = threadIdx.x;
  const float4* xr = (const float4*)(X + (long)r * 1152);
  float4 v0 = xr[t];
  float4 v1 = make_float4(0.f, 0.f, 0.f, 0.f);
  bool two = t < 32;                         // 288 float4 per row
  if (two) v1 = xr[256 + t];
  float s = v0.x + v0.y + v0.z + v0.w + v1.x + v1.y + v1.z + v1.w;
  float q = v0.x * v0.x + v0.y * v0.y + v0.z * v0.z + v0.w * v0.w +
            v1.x * v1.x + v1.y * v1.y + v1.z * v1.z + v1.w * v1.w;
#pragma unroll
  for (int m = 32; m > 0; m >>= 1) { s += __shfl_xor(s, m); q += __shfl_xor(q, m); }
  __shared__ float ss[4], sq[4];
  if ((t & 63) == 0) { ss[t >> 6] = s; sq[t >> 6] = q; }
  __syncthreads();
  s = ss[0] + ss[1] + ss[2] + ss[3];
  q = sq[0] + sq[1] + sq[2] + sq[3];
  const float inv = 1.f / 1152.f;
  float mu = s * inv;
  float var = q * inv - mu * mu;
  float rs = rsqrtf(var + 1e-6f);
  const float4* sh = (const float4*)(ada + b * 6912 + so);
  const float4* sc = (const float4*)(ada + b * 6912 + co);
  u16* orow = out + (long)r * 1152;
  {
    float4 hv = sh[t], cv = sc[t];
    union { u16 u[4]; uint2 d; } p;
    p.u[0] = f2b((v0.x - mu) * rs * (1.f + cv.x) + hv.x);
    p.u[1] = f2b((v0.y - mu) * rs * (1.f + cv.y) + hv.y);
    p.u[2] = f2b((v0.z - mu) * rs * (1.f + cv.z) + hv.z);
    p.u[3] = f2b((v0.w - mu) * rs * (1.f + cv.w) + hv.w);
    ((uint2*)orow)[t] = p.d;
  }
  if (two) {
    float4 hv = sh[256 + t], cv = sc[256 + t];
    union { u16 u[4]; uint2 d; } p;
    p.u[0] = f2b((v1.x - mu) * rs * (1.f + cv.x) + hv.x);
    p.u[1] = f2b((v1.y - mu) * rs * (1.f + cv.y) + hv.y);
    p.u[2] = f2b((v1.z - mu) * rs * (1.f + cv.z) + hv.z);
    p.u[3] = f2b((v1.w - mu) * rs * (1.f + cv.w) + hv.w);
    ((uint2*)orow)[256 + t] = p.d;
  }
}

// ---------- out = res + gate*bias  (fc2 split-K epilogue base) ----------
__global__ __launch_bounds__(256) void out_init(const float* __restrict__ res,
                                                const float* __restrict__ ada,
                                                const float* __restrict__ bias,
                                                float* __restrict__ out) {
  int r = blockIdx.x, b = r >> 10, t = threadIdx.x;
  const float4* rr = (const float4*)(res + (long)r * 1152);
  const float4* bb = (const float4*)bias;
  const float4* gg = (const float4*)(ada + b * 6912 + 5760);
  float4* oo = (float4*)(out + (long)r * 1152);
  for (int i = t; i < 288; i += 256) {
    float4 rv = rr[i], bv = bb[i], gv = gg[i];
    oo[i] = make_float4(rv.x + gv.x * bv.x, rv.y + gv.y * bv.y,
                        rv.z + gv.z * bv.z, rv.w + gv.w * bv.w);
  }
}

// ---------- V [bh][1024][96] -> Vt [bh][96][1024] ----------
__global__ __launch_bounds__(256) void transpose_v(const u16* __restrict__ V,
                                                   u16* __restrict__ Vt) {
  __shared__ u16 t[32][33];
  long zofs = (long)blockIdx.z * 98304;
  int d0 = blockIdx.x * 32, l0 = blockIdx.y * 32;
  int tx = threadIdx.x & 31, ty = threadIdx.x >> 5;
#pragma unroll
  for (int i = 0; i < 32; i += 8)
    t[ty + i][tx] = V[zofs + (long)(l0 + ty + i) * 96 + d0 + tx];
  __syncthreads();
#pragma unroll
  for (int i = 0; i < 32; i += 8)
    Vt[zofs + (long)(d0 + ty + i) * 1024 + l0 + tx] = t[tx][ty + i];
}

// ---------- fused flash attention ----------
// 1D grid 1024 = 8 q-tiles x 128 bh, XCD-swizzled so each XCD owns 16
// consecutive bh (all 8 q-tiles) -> K/V L2-resident per XCD (T1).
// 4 waves x 32 q-rows; KV-tiles of 128. Occupancy: 4 blocks/CU (T5 regime).
__global__ __launch_bounds__(256, 4) void flash_attn(
    const u16* __restrict__ Q, const u16* __restrict__ K,
    const u16* __restrict__ Vt, u16* __restrict__ Oa) {
  __shared__ __align__(16) u16 Plds[4][4096];   // 8KB per wave, wave-private
  const int lane = threadIdx.x & 63, w = threadIdx.x >> 6;
  const int lr = lane & 15, lg = lane >> 4;
  // T1 swizzle: hw assigns linear bid round-robin to XCDs (bid&7)
  const int work = (blockIdx.x & 7) * 128 + (blockIdx.x >> 3);
  const int bh = work >> 3;
  const int q0 = (work & 7) * 128 + w * 32;
  const u16* Qp = Q + (long)bh * 98304;
  const u16* Kp = K + (long)bh * 98304;
  const u16* Vp = Vt + (long)bh * 98304;
  char* pl = (char*)&Plds[w][0];

  bf16x8 qf[2][3];
#pragma unroll
  for (int i = 0; i < 2; ++i)
#pragma unroll
    for (int kk = 0; kk < 3; ++kk)
      qf[i][kk] = *(const bf16x8*)(Qp + (long)(q0 + i * 16 + lr) * 96 + kk * 32 + lg * 8);

  f32x4 o[2][5] = {};                        // cols 0..79 only (d<72 kept)
  float mrow[2][4], lrow[2][4];
#pragma unroll
  for (int i = 0; i < 2; ++i)
#pragma unroll
    for (int r = 0; r < 4; ++r) { mrow[i][r] = -3e38f; lrow[i][r] = 0.f; }

  for (int kt = 0; kt < 8; ++kt) {
    const int kv0 = kt * 128;
    f32x4 s[2][8] = {};
    __builtin_amdgcn_s_setprio(1);           // T5 (m191: +4-7% attn)
#pragma unroll
    for (int j = 0; j < 8; ++j) {
      const u16* kp = Kp + (long)(kv0 + j * 16 + lr) * 96 + lg * 8;
      bf16x8 k0 = *(const bf16x8*)kp;
      bf16x8 k1 = *(const bf16x8*)(kp + 32);
      bf16x8 k2 = *(const bf16x8*)(kp + 64);
#pragma unroll
      for (int i = 0; i < 2; ++i) {
        s[i][j] = __builtin_amdgcn_mfma_f32_16x16x32_bf16(qf[i][0], k0, s[i][j], 0, 0, 0);
        s[i][j] = __builtin_amdgcn_mfma_f32_16x16x32_bf16(qf[i][1], k1, s[i][j], 0, 0, 0);
        s[i][j] = __builtin_amdgcn_mfma_f32_16x16x32_bf16(qf[i][2], k2, s[i][j], 0, 0, 0);
      }
    }
    __builtin_amdgcn_s_setprio(0);
    float mx[2][4];
#pragma unroll
    for (int i = 0; i < 2; ++i)
#pragma unroll
      for (int r = 0; r < 4; ++r) {
        float m0 = s[i][0][r];
#pragma unroll
        for (int j = 1; j < 8; ++j) m0 = fmaxf(m0, s[i][j][r]);
        mx[i][r] = m0;
      }
#pragma unroll
    for (int mk = 1; mk < 16; mk <<= 1)
#pragma unroll
      for (int i = 0; i < 2; ++i)
#pragma unroll
        for (int r = 0; r < 4; ++r) mx[i][r] = fmaxf(mx[i][r], __shfl_xor(mx[i][r], mk));
#pragma unroll
    for (int i = 0; i < 2; ++i)
#pragma unroll
      for (int r = 0; r < 4; ++r) {
        float nm = fmaxf(mrow[i][r], mx[i][r]);
        float sc = __expf(mrow[i][r] - nm);
        mrow[i][r] = nm;
        lrow[i][r] *= sc;
#pragma unroll
        for (int n = 0; n < 5; ++n) o[i][n][r] *= sc;
      }
    float ps[2][4] = {};
#pragma unroll
    for (int i = 0; i < 2; ++i)
#pragma unroll
      for (int j = 0; j < 8; ++j)
#pragma unroll
        for (int r = 0; r < 4; ++r) {
          float p = __expf(s[i][j][r] - mrow[i][r]);
          ps[i][r] += p;
          const int row = i * 16 + lg * 4 + r;
          const int byte = (row * 256 + (j * 16 + lr) * 2) ^ ((row & 7) << 4);
          *(u16*)(pl + byte) = f2b(p);
        }
#pragma unroll
    for (int mk = 1; mk < 16; mk <<= 1)
#pragma unroll
      for (int i = 0; i < 2; ++i)
#pragma unroll
        for (int r = 0; r < 4; ++r) ps[i][r] += __shfl_xor(ps[i][r], mk);
#pragma unroll
    for (int i = 0; i < 2; ++i)
#pragma unroll
      for (int r = 0; r < 4; ++r) lrow[i][r] += ps[i][r];
    bf16x8 pa[2][4];
#pragma unroll
    for (int i = 0; i < 2; ++i)
#pragma unroll
      for (int ks = 0; ks < 4; ++ks) {
        const int byte = ((i * 16 + lr) * 256 + (ks * 32 + lg * 8) * 2) ^ ((lr & 7) << 4);
        pa[i][ks] = *(const bf16x8*)(pl + byte);
      }
    __builtin_amdgcn_s_setprio(1);
#pragma unroll
    for (int n = 0; n < 5; ++n) {
#pragma unroll
      for (int ks = 0; ks < 4; ++ks) {
        bf16x8 vf = *(const bf16x8*)(Vp + (long)(n * 16 + lr) * 1024 + kv0 + ks * 32 + lg * 8);
#pragma unroll
        for (int i = 0; i < 2; ++i)
          o[i][n] = __builtin_amdgcn_mfma_f32_16x16x32_bf16(pa[i][ks], vf, o[i][n], 0, 0, 0);
      }
    }
    __builtin_amdgcn_s_setprio(0);
  }
  const int b = bh >> 4, h = bh & 15;
#pragma unroll
  for (int i = 0; i < 2; ++i)
#pragma unroll
    for (int r = 0; r < 4; ++r) {
      const int l = q0 + i * 16 + lg * 4 + r;
      const float rinv = 1.f / lrow[i][r];
      u16* orow = Oa + ((long)b * 1024 + l) * 1152 + h * 72;
#pragma unroll
      for (int n = 0; n < 5; ++n) {
        const int col = n * 16 + lr;
        if (col < 72) orow[col] = f2b(o[i][n][r] * rinv);
      }
    }
}

// ---------- main bf16 GEMM: C = A(MxK) @ Bt(NxK)^T ----------
// Single-buffered 16KB LDS (max TLP; R6 dbuf halved occupancy for net 0).
// T1 XCD swizzle: contiguous work chunks per XCD share B-panels in L2.
// MODE 1: qkv: +bias, scatter to Q(scaled)/K/V [bh][l][96]
// MODE 3: proj: out = res + gate*(acc+bias)  (fp32)
// MODE 4: fc1: gelu_tanh(acc+bias) -> bf16
// MODE 6: fc2 split-K: atomicAdd(out, gate*acc); bias handled by out_init
template <int TM, int TN, int MODE>
__global__ __launch_bounds__(256) void gemm_bt(
    const u16* __restrict__ A, const u16* __restrict__ Bt, int Kd, int ldc,
    int ksplit, const float* __restrict__ bias, void* __restrict__ outp,
    const float* __restrict__ res, const float* __restrict__ ada, int gofs,
    u16* __restrict__ qb, u16* __restrict__ kb, u16* __restrict__ vb) {
  constexpr int BM = TM * 32, BN = TN * 32;  // 2x2 waves of TMxTN 16-tiles
  __shared__ __align__(16) u16 lA[BM * 32];
  __shared__ __align__(16) u16 lB[BN * 32];
  const int tid = threadIdx.x, lane = tid & 63, w = tid >> 6;
  const int wr = w >> 1, wc = w & 1, lr = lane & 15, lg = lane >> 4;
  // T1 chunked-bijective swizzle (gx*gy % 8 == 0 for all our grids)
  const int gx = gridDim.x;
  const int lin = blockIdx.x + gx * blockIdx.y;
  const int cpx = (gx * gridDim.y) >> 3;
  const int work = (lin & 7) * cpx + (lin >> 3);
  const int bx = work % gx, by = work / gx;
  const int nk = (Kd / ksplit) >> 5;                  // K-steps this block owns
  const long k0 = (long)blockIdx.z * (Kd / ksplit);   // split-K base
  const u16* Ab = A + (long)bx * BM * Kd + k0;
  const u16* Bb = Bt + (long)by * BN * Kd + k0;
  const int srow = lane >> 2, scol = (lane & 3) * 8;
  const u16* ga0 = Ab + (long)srow * Kd + scol;
  const u16* gb0 = Bb + (long)srow * Kd + scol;

  f32x4 acc[TM][TN] = {};
  for (int kt = 0; kt < nk; ++kt) {
    for (int ch = w; ch < BM / 16; ch += 4)
      gload16(ga0 + (long)(ch * 16) * Kd + kt * 32, &lA[ch * 512]);
    for (int ch = w; ch < BN / 16; ch += 4)
      gload16(gb0 + (long)(ch * 16) * Kd + kt * 32, &lB[ch * 512]);
    __syncthreads();
    bf16x8 af[TM], bfr[TN];
#pragma unroll
    for (int i = 0; i < TM; ++i)
      af[i] = *(const bf16x8*)&lA[(wr * TM * 16 + i * 16 + lr) * 32 + lg * 8];
#pragma unroll
    for (int j = 0; j < TN; ++j)
      bfr[j] = *(const bf16x8*)&lB[(wc * TN * 16 + j * 16 + lr) * 32 + lg * 8];
#pragma unroll
    for (int i = 0; i < TM; ++i)
#pragma unroll
      for (int j = 0; j < TN; ++j)
        acc[i][j] = __builtin_amdgcn_mfma_f32_16x16x32_bf16(af[i], bfr[j], acc[i][j], 0, 0, 0);
    __syncthreads();
  }

#pragma unroll
  for (int i = 0; i < TM; ++i) {
#pragma unroll
    for (int j = 0; j < TN; ++j) {
#pragma unroll
      for (int r = 0; r < 4; ++r) {
        const int row = bx * BM + wr * TM * 16 + i * 16 + lg * 4 + r;
        const int col = by * BN + wc * TN * 16 + j * 16 + lr;
        float val = acc[i][j][r];
        if (MODE == 1) {
          val += bias[col];
          int sel = col / 1152, cc = col - sel * 1152;
          int hh = cc / 72, dd = cc - hh * 72;
          int bb = row >> 10, ll = row & 1023;
          long idx = ((long)(bb * 16 + hh) * 1024 + ll) * 96 + dd;
          if (sel == 0) qb[idx] = f2b(val * 0.11785113019775793f);  // 72^-0.5
          else if (sel == 1) kb[idx] = f2b(val);
          else vb[idx] = f2b(val);
        } else if (MODE == 3) {
          val += bias[col];
          float* o = (float*)outp;
          long idx = (long)row * 1152 + col;
          o[idx] = res[idx] + ada[(row >> 10) * 6912 + gofs + col] * val;
        } else if (MODE == 4) {
          val += bias[col];
          float t2 = 0.7978845608028654f * (val + 0.044715f * val * val * val);
          t2 = fminf(fmaxf(t2, -15.f), 15.f);
          float e2 = __expf(2.f * t2);
          float th = 1.f - 2.f / (e2 + 1.f);
          ((u16*)outp)[(long)row * ldc + col] = f2b(0.5f * val * (1.f + th));
        } else if (MODE == 6) {
          float* o = (float*)outp;
          long idx = (long)row * 1152 + col;
          atomicAdd(&o[idx], ada[(row >> 10) * 6912 + gofs + col] * val);
        }
      }
    }
  }
}

// ---------- host ----------
extern "C" void kernel_launch(void* const* d_in, const int* in_sizes, int n_in,
                              void* d_out, int out_size, void* d_ws, size_t ws_size,
                              hipStream_t stream) {
  const float* x    = (const float*)d_in[0];
  const float* c    = (const float*)d_in[1];
  const float* Wqkv = (const float*)d_in[2];
  const float* bqkv = (const float*)d_in[3];
  const float* Wprj = (const float*)d_in[4];
  const float* bprj = (const float*)d_in[5];
  const float* Wfc1 = (const float*)d_in[6];
  const float* bfc1 = (const float*)d_in[7];
  const float* Wfc2 = (const float*)d_in[8];
  const float* bfc2 = (const float*)d_in[9];
  const float* Wada = (const float*)d_in[10];
  const float* bada = (const float*)d_in[11];

  char* ws = (char*)d_ws;
  size_t o = 0;
  auto alloc = [&](size_t bytes) -> char* {
    char* p = ws + o;
    o += (bytes + 255) & ~(size_t)255;
    return p;
  };
  u16* wqkvT = (u16*)alloc(3456ull * 1152 * 2);
  u16* wprjT = (u16*)alloc(1152ull * 1152 * 2);
  u16* wfc1T = (u16*)alloc(4608ull * 1152 * 2);
  u16* wfc2T = (u16*)alloc(1152ull * 4608 * 2);
  float* adab = (float*)alloc(8ull * 6912 * 4);
  u16* hbuf = (u16*)alloc(8192ull * 1152 * 2);
  u16* Qb   = (u16*)alloc(25165824);           // [128][1024][96] bf16
  u16* Kb   = (u16*)alloc(25165824);
  u16* Vt   = (u16*)alloc(25165824);           // [128][96][1024]
  u16* attn = (u16*)alloc(8192ull * 1152 * 2);
  float* x2 = (float*)alloc(8192ull * 1152 * 4);
  u16* Vb = (u16*)x2;                          // V [bh][1024][96]; dead before x2 written
  u16* hmid = Qb;                              // fc1 out aliases Qb/Kb/Vt (75.5 MB), attn done

  // weights -> bf16 transposed
  wt_bf16<<<dim3(108, 36), 256, 0, stream>>>(Wqkv, wqkvT, 1152, 3456);
  wt_bf16<<<dim3(36, 36), 256, 0, stream>>>(Wprj, wprjT, 1152, 1152);
  wt_bf16<<<dim3(144, 36), 256, 0, stream>>>(Wfc1, wfc1T, 1152, 4608);
  wt_bf16<<<dim3(36, 144), 256, 0, stream>>>(Wfc2, wfc2T, 4608, 1152);
  // adaLN vectors
  ada_gemm<<<108, 512, 0, stream>>>(c, Wada, bada, adab);
  // zero Q,K pads (cols 72..95 feed the QK^T contraction) and V pads
  hipMemsetAsync(Qb, 0, 2ull * 25165824, stream);
  hipMemsetAsync(Vb, 0, 25165824, stream);
  // LN1 + modulate(shift_msa, scale_msa)
  ln_mod<<<8192, 256, 0, stream>>>(x, adab, 0, 1152, hbuf);
  // QKV projection + scatter
  gemm_bt<4, 4, 1><<<dim3(64, 27), 256, 0, stream>>>(
      hbuf, wqkvT, 1152, 0, 1, bqkv, nullptr, nullptr, nullptr, 0, Qb, Kb, Vb);
  transpose_v<<<dim3(3, 32, 128), 256, 0, stream>>>(Vb, Vt);
  // fused attention -> attn bf16 (XCD-swizzled 1D grid)
  flash_attn<<<dim3(1024), 256, 0, stream>>>(Qb, Kb, Vt, attn);
  // proj + residual + gate_msa -> x2 (fp32)
  gemm_bt<2, 4, 3><<<dim3(128, 9), 256, 0, stream>>>(
      attn, wprjT, 1152, 1152, 1, bprj, x2, x, adab, 2304, nullptr, nullptr, nullptr);
  // LN2 + modulate(shift_mlp, scale_mlp)
  ln_mod<<<8192, 256, 0, stream>>>(x2, adab, 3456, 4608, hbuf);
  // fc1 + gelu
  gemm_bt<4, 4, 4><<<dim3(64, 36), 256, 0, stream>>>(
      hbuf, wfc1T, 1152, 4608, 1, bfc1, hmid, nullptr, nullptr, 0, nullptr, nullptr, nullptr);
  // fc2: d_out = res + gate*bias, then split-K=2 blocks atomicAdd gate*partial
  out_init<<<8192, 256, 0, stream>>>(x2, adab, bfc2, (float*)d_out);
  gemm_bt<4, 4, 6><<<dim3(64, 9, 2), 256, 0, stream>>>(
      hmid, wfc2T, 4608, 1152, 2, nullptr, d_out, nullptr, adab, 5760,
      nullptr, nullptr, nullptr);
}

// Round 12
// 934.783 us; speedup vs baseline: 1.2802x; 1.2802x over previous
//
#include <hip/hip_runtime.h>
#include <stdint.h>

#define DEV static __device__ __forceinline__

typedef __attribute__((ext_vector_type(8))) __bf16 bf16x8;
typedef __attribute__((ext_vector_type(4))) float f32x4;
typedef unsigned short u16;
typedef unsigned int u32;

// ---------- scalar helpers ----------
DEV u16 f2b(float f) {                       // fp32 -> bf16 bits, RN-even
  u32 u = __float_as_uint(f);
  u32 r = (u + 0x7FFFu + ((u >> 16) & 1u)) >> 16;
  return (u16)r;
}

DEV void gload16(const u16* g, u16* l) {     // async global->LDS, 16B/lane
  __builtin_amdgcn_global_load_lds(
      (const __attribute__((address_space(1))) u32*)g,
      (__attribute__((address_space(3))) u32*)l, 16, 0, 0);
}

// ---------- W (K x N fp32, row-major) -> Wt (N x K bf16) ----------
__global__ __launch_bounds__(256) void wt_bf16(const float* __restrict__ W,
                                               u16* __restrict__ Wt, int K, int N) {
  __shared__ float t[32][33];
  int n0 = blockIdx.x * 32, k0 = blockIdx.y * 32;
  int tx = threadIdx.x & 31, ty = threadIdx.x >> 5;   // ty 0..7
#pragma unroll
  for (int i = 0; i < 32; i += 8)
    t[ty + i][tx] = W[(long)(k0 + ty + i) * N + n0 + tx];
  __syncthreads();
#pragma unroll
  for (int i = 0; i < 32; i += 8)
    Wt[(long)(n0 + ty + i) * K + k0 + tx] = f2b(t[tx][ty + i]);
}

// ---------- ada = silu(c) @ W_ada + b_ada  (8 x 6912) ----------
__global__ __launch_bounds__(512) void ada_gemm(const float* __restrict__ c,
                                                const float* __restrict__ W,
                                                const float* __restrict__ bias,
                                                float* __restrict__ ada) {
  __shared__ float sc[8 * 1152];
  int t = threadIdx.x;
  for (int i = t; i < 8 * 1152; i += 512) {
    float v = c[i];
    sc[i] = v / (1.f + __expf(-v));
  }
  __syncthreads();
  int n = blockIdx.x * 64 + (t & 63), b = t >> 6;
  const float* wp = W + n;
  const float* scp = sc + b * 1152;
  float acc = 0.f;
#pragma unroll 8
  for (int k = 0; k < 1152; ++k) acc = fmaf(scp[k], wp[(long)k * 6912], acc);
  ada[b * 6912 + n] = acc + bias[n];
}

// ---------- LayerNorm + modulate -> bf16 ----------
__global__ __launch_bounds__(256) void ln_mod(const float* __restrict__ X,
                                              const float* __restrict__ ada,
                                              int so, int co, u16* __restrict__ out) {
  int r = blockIdx.x, b = r >> 10, t = threadIdx.x;
  const float4* xr = (const float4*)(X + (long)r * 1152);
  float4 v0 = xr[t];
  float4 v1 = make_float4(0.f, 0.f, 0.f, 0.f);
  bool two = t < 32;                         // 288 float4 per row
  if (two) v1 = xr[256 + t];
  float s = v0.x + v0.y + v0.z + v0.w + v1.x + v1.y + v1.z + v1.w;
  float q = v0.x * v0.x + v0.y * v0.y + v0.z * v0.z + v0.w * v0.w +
            v1.x * v1.x + v1.y * v1.y + v1.z * v1.z + v1.w * v1.w;
#pragma unroll
  for (int m = 32; m > 0; m >>= 1) { s += __shfl_xor(s, m); q += __shfl_xor(q, m); }
  __shared__ float ss[4], sq[4];
  if ((t & 63) == 0) { ss[t >> 6] = s; sq[t >> 6] = q; }
  __syncthreads();
  s = ss[0] + ss[1] + ss[2] + ss[3];
  q = sq[0] + sq[1] + sq[2] + sq[3];
  const float inv = 1.f / 1152.f;
  float mu = s * inv;
  float var = q * inv - mu * mu;
  float rs = rsqrtf(var + 1e-6f);
  const float4* sh = (const float4*)(ada + b * 6912 + so);
  const float4* sc = (const float4*)(ada + b * 6912 + co);
  u16* orow = out + (long)r * 1152;
  {
    float4 hv = sh[t], cv = sc[t];
    union { u16 u[4]; uint2 d; } p;
    p.u[0] = f2b((v0.x - mu) * rs * (1.f + cv.x) + hv.x);
    p.u[1] = f2b((v0.y - mu) * rs * (1.f + cv.y) + hv.y);
    p.u[2] = f2b((v0.z - mu) * rs * (1.f + cv.z) + hv.z);
    p.u[3] = f2b((v0.w - mu) * rs * (1.f + cv.w) + hv.w);
    ((uint2*)orow)[t] = p.d;
  }
  if (two) {
    float4 hv = sh[256 + t], cv = sc[256 + t];
    union { u16 u[4]; uint2 d; } p;
    p.u[0] = f2b((v1.x - mu) * rs * (1.f + cv.x) + hv.x);
    p.u[1] = f2b((v1.y - mu) * rs * (1.f + cv.y) + hv.y);
    p.u[2] = f2b((v1.z - mu) * rs * (1.f + cv.z) + hv.z);
    p.u[3] = f2b((v1.w - mu) * rs * (1.f + cv.w) + hv.w);
    ((uint2*)orow)[256 + t] = p.d;
  }
}

// ---------- out = res + gate*bias  (fc2 split-K epilogue base) ----------
__global__ __launch_bounds__(256) void out_init(const float* __restrict__ res,
                                                const float* __restrict__ ada,
                                                const float* __restrict__ bias,
                                                float* __restrict__ out) {
  int r = blockIdx.x, b = r >> 10, t = threadIdx.x;
  const float4* rr = (const float4*)(res + (long)r * 1152);
  const float4* bb = (const float4*)bias;
  const float4* gg = (const float4*)(ada + b * 6912 + 5760);
  float4* oo = (float4*)(out + (long)r * 1152);
  for (int i = t; i < 288; i += 256) {
    float4 rv = rr[i], bv = bb[i], gv = gg[i];
    oo[i] = make_float4(rv.x + gv.x * bv.x, rv.y + gv.y * bv.y,
                        rv.z + gv.z * bv.z, rv.w + gv.w * bv.w);
  }
}

// ---------- V [bh][1024][96] -> Vt [bh][96][1024] ----------
__global__ __launch_bounds__(256) void transpose_v(const u16* __restrict__ V,
                                                   u16* __restrict__ Vt) {
  __shared__ u16 t[32][33];
  long zofs = (long)blockIdx.z * 98304;
  int d0 = blockIdx.x * 32, l0 = blockIdx.y * 32;
  int tx = threadIdx.x & 31, ty = threadIdx.x >> 5;
#pragma unroll
  for (int i = 0; i < 32; i += 8)
    t[ty + i][tx] = V[zofs + (long)(l0 + ty + i) * 96 + d0 + tx];
  __syncthreads();
#pragma unroll
  for (int i = 0; i < 32; i += 8)
    Vt[zofs + (long)(d0 + ty + i) * 1024 + l0 + tx] = t[tx][ty + i];
}

// ---------- fused flash attention ----------
// 1D grid 1024, T1 XCD swizzle (K/V L2 reuse). launch_bounds(256,2):
// R11 post-mortem — true register need ~184/lane (acc regs not in the
// reported 120); any bound >2 waves/EU spills to scratch (534MB writes,
// 2.2x slowdown). Occupancy gains here require KVBLK=64 reg relief, not
// a tighter bound.
__global__ __launch_bounds__(256, 2) void flash_attn(
    const u16* __restrict__ Q, const u16* __restrict__ K,
    const u16* __restrict__ Vt, u16* __restrict__ Oa) {
  __shared__ __align__(16) u16 Plds[4][4096];   // 8KB per wave, wave-private
  const int lane = threadIdx.x & 63, w = threadIdx.x >> 6;
  const int lr = lane & 15, lg = lane >> 4;
  // T1 swizzle: hw assigns linear bid round-robin to XCDs (bid&7)
  const int work = (blockIdx.x & 7) * 128 + (blockIdx.x >> 3);
  const int bh = work >> 3;
  const int q0 = (work & 7) * 128 + w * 32;
  const u16* Qp = Q + (long)bh * 98304;
  const u16* Kp = K + (long)bh * 98304;
  const u16* Vp = Vt + (long)bh * 98304;
  char* pl = (char*)&Plds[w][0];

  bf16x8 qf[2][3];
#pragma unroll
  for (int i = 0; i < 2; ++i)
#pragma unroll
    for (int kk = 0; kk < 3; ++kk)
      qf[i][kk] = *(const bf16x8*)(Qp + (long)(q0 + i * 16 + lr) * 96 + kk * 32 + lg * 8);

  f32x4 o[2][5] = {};                        // cols 0..79 only (d<72 kept)
  float mrow[2][4], lrow[2][4];
#pragma unroll
  for (int i = 0; i < 2; ++i)
#pragma unroll
    for (int r = 0; r < 4; ++r) { mrow[i][r] = -3e38f; lrow[i][r] = 0.f; }

  for (int kt = 0; kt < 8; ++kt) {
    const int kv0 = kt * 128;
    f32x4 s[2][8] = {};
    __builtin_amdgcn_s_setprio(1);           // T5 (m191: +4-7% attn)
#pragma unroll
    for (int j = 0; j < 8; ++j) {
      const u16* kp = Kp + (long)(kv0 + j * 16 + lr) * 96 + lg * 8;
      bf16x8 k0 = *(const bf16x8*)kp;
      bf16x8 k1 = *(const bf16x8*)(kp + 32);
      bf16x8 k2 = *(const bf16x8*)(kp + 64);
#pragma unroll
      for (int i = 0; i < 2; ++i) {
        s[i][j] = __builtin_amdgcn_mfma_f32_16x16x32_bf16(qf[i][0], k0, s[i][j], 0, 0, 0);
        s[i][j] = __builtin_amdgcn_mfma_f32_16x16x32_bf16(qf[i][1], k1, s[i][j], 0, 0, 0);
        s[i][j] = __builtin_amdgcn_mfma_f32_16x16x32_bf16(qf[i][2], k2, s[i][j], 0, 0, 0);
      }
    }
    __builtin_amdgcn_s_setprio(0);
    float mx[2][4];
#pragma unroll
    for (int i = 0; i < 2; ++i)
#pragma unroll
      for (int r = 0; r < 4; ++r) {
        float m0 = s[i][0][r];
#pragma unroll
        for (int j = 1; j < 8; ++j) m0 = fmaxf(m0, s[i][j][r]);
        mx[i][r] = m0;
      }
#pragma unroll
    for (int mk = 1; mk < 16; mk <<= 1)
#pragma unroll
      for (int i = 0; i < 2; ++i)
#pragma unroll
        for (int r = 0; r < 4; ++r) mx[i][r] = fmaxf(mx[i][r], __shfl_xor(mx[i][r], mk));
#pragma unroll
    for (int i = 0; i < 2; ++i)
#pragma unroll
      for (int r = 0; r < 4; ++r) {
        float nm = fmaxf(mrow[i][r], mx[i][r]);
        float sc = __expf(mrow[i][r] - nm);
        mrow[i][r] = nm;
        lrow[i][r] *= sc;
#pragma unroll
        for (int n = 0; n < 5; ++n) o[i][n][r] *= sc;
      }
    float ps[2][4] = {};
#pragma unroll
    for (int i = 0; i < 2; ++i)
#pragma unroll
      for (int j = 0; j < 8; ++j)
#pragma unroll
        for (int r = 0; r < 4; ++r) {
          float p = __expf(s[i][j][r] - mrow[i][r]);
          ps[i][r] += p;
          const int row = i * 16 + lg * 4 + r;
          const int byte = (row * 256 + (j * 16 + lr) * 2) ^ ((row & 7) << 4);
          *(u16*)(pl + byte) = f2b(p);
        }
#pragma unroll
    for (int mk = 1; mk < 16; mk <<= 1)
#pragma unroll
      for (int i = 0; i < 2; ++i)
#pragma unroll
        for (int r = 0; r < 4; ++r) ps[i][r] += __shfl_xor(ps[i][r], mk);
#pragma unroll
    for (int i = 0; i < 2; ++i)
#pragma unroll
      for (int r = 0; r < 4; ++r) lrow[i][r] += ps[i][r];
    bf16x8 pa[2][4];
#pragma unroll
    for (int i = 0; i < 2; ++i)
#pragma unroll
      for (int ks = 0; ks < 4; ++ks) {
        const int byte = ((i * 16 + lr) * 256 + (ks * 32 + lg * 8) * 2) ^ ((lr & 7) << 4);
        pa[i][ks] = *(const bf16x8*)(pl + byte);
      }
    __builtin_amdgcn_s_setprio(1);
#pragma unroll
    for (int n = 0; n < 5; ++n) {
#pragma unroll
      for (int ks = 0; ks < 4; ++ks) {
        bf16x8 vf = *(const bf16x8*)(Vp + (long)(n * 16 + lr) * 1024 + kv0 + ks * 32 + lg * 8);
#pragma unroll
        for (int i = 0; i < 2; ++i)
          o[i][n] = __builtin_amdgcn_mfma_f32_16x16x32_bf16(pa[i][ks], vf, o[i][n], 0, 0, 0);
      }
    }
    __builtin_amdgcn_s_setprio(0);
  }
  const int b = bh >> 4, h = bh & 15;
#pragma unroll
  for (int i = 0; i < 2; ++i)
#pragma unroll
    for (int r = 0; r < 4; ++r) {
      const int l = q0 + i * 16 + lg * 4 + r;
      const float rinv = 1.f / lrow[i][r];
      u16* orow = Oa + ((long)b * 1024 + l) * 1152 + h * 72;
#pragma unroll
      for (int n = 0; n < 5; ++n) {
        const int col = n * 16 + lr;
        if (col < 72) orow[col] = f2b(o[i][n][r] * rinv);
      }
    }
}

// ---------- main bf16 GEMM: C = A(MxK) @ Bt(NxK)^T ----------
// Single-buffered 16KB LDS. No XCD swizzle: all operands L3-fit, where
// swizzle is measured ~-2% (m160); R11 confirmed ~neutral-negative.
// MODE 1: qkv: +bias, scatter to Q(scaled)/K/V [bh][l][96]
// MODE 3: proj: out = res + gate*(acc+bias)  (fp32)
// MODE 4: fc1: gelu_tanh(acc+bias) -> bf16
// MODE 6: fc2 split-K: atomicAdd(out, gate*acc); bias handled by out_init
template <int TM, int TN, int MODE>
__global__ __launch_bounds__(256) void gemm_bt(
    const u16* __restrict__ A, const u16* __restrict__ Bt, int Kd, int ldc,
    int ksplit, const float* __restrict__ bias, void* __restrict__ outp,
    const float* __restrict__ res, const float* __restrict__ ada, int gofs,
    u16* __restrict__ qb, u16* __restrict__ kb, u16* __restrict__ vb) {
  constexpr int BM = TM * 32, BN = TN * 32;  // 2x2 waves of TMxTN 16-tiles
  __shared__ __align__(16) u16 lA[BM * 32];
  __shared__ __align__(16) u16 lB[BN * 32];
  const int tid = threadIdx.x, lane = tid & 63, w = tid >> 6;
  const int wr = w >> 1, wc = w & 1, lr = lane & 15, lg = lane >> 4;
  const int bx = blockIdx.x, by = blockIdx.y;
  const int nk = (Kd / ksplit) >> 5;                  // K-steps this block owns
  const long k0 = (long)blockIdx.z * (Kd / ksplit);   // split-K base
  const u16* Ab = A + (long)bx * BM * Kd + k0;
  const u16* Bb = Bt + (long)by * BN * Kd + k0;
  const int srow = lane >> 2, scol = (lane & 3) * 8;
  const u16* ga0 = Ab + (long)srow * Kd + scol;
  const u16* gb0 = Bb + (long)srow * Kd + scol;

  f32x4 acc[TM][TN] = {};
  for (int kt = 0; kt < nk; ++kt) {
    for (int ch = w; ch < BM / 16; ch += 4)
      gload16(ga0 + (long)(ch * 16) * Kd + kt * 32, &lA[ch * 512]);
    for (int ch = w; ch < BN / 16; ch += 4)
      gload16(gb0 + (long)(ch * 16) * Kd + kt * 32, &lB[ch * 512]);
    __syncthreads();
    bf16x8 af[TM], bfr[TN];
#pragma unroll
    for (int i = 0; i < TM; ++i)
      af[i] = *(const bf16x8*)&lA[(wr * TM * 16 + i * 16 + lr) * 32 + lg * 8];
#pragma unroll
    for (int j = 0; j < TN; ++j)
      bfr[j] = *(const bf16x8*)&lB[(wc * TN * 16 + j * 16 + lr) * 32 + lg * 8];
#pragma unroll
    for (int i = 0; i < TM; ++i)
#pragma unroll
      for (int j = 0; j < TN; ++j)
        acc[i][j] = __builtin_amdgcn_mfma_f32_16x16x32_bf16(af[i], bfr[j], acc[i][j], 0, 0, 0);
    __syncthreads();
  }

#pragma unroll
  for (int i = 0; i < TM; ++i) {
#pragma unroll
    for (int j = 0; j < TN; ++j) {
#pragma unroll
      for (int r = 0; r < 4; ++r) {
        const int row = bx * BM + wr * TM * 16 + i * 16 + lg * 4 + r;
        const int col = by * BN + wc * TN * 16 + j * 16 + lr;
        float val = acc[i][j][r];
        if (MODE == 1) {
          val += bias[col];
          int sel = col / 1152, cc = col - sel * 1152;
          int hh = cc / 72, dd = cc - hh * 72;
          int bb = row >> 10, ll = row & 1023;
          long idx = ((long)(bb * 16 + hh) * 1024 + ll) * 96 + dd;
          if (sel == 0) qb[idx] = f2b(val * 0.11785113019775793f);  // 72^-0.5
          else if (sel == 1) kb[idx] = f2b(val);
          else vb[idx] = f2b(val);
        } else if (MODE == 3) {
          val += bias[col];
          float* o = (float*)outp;
          long idx = (long)row * 1152 + col;
          o[idx] = res[idx] + ada[(row >> 10) * 6912 + gofs + col] * val;
        } else if (MODE == 4) {
          val += bias[col];
          float t2 = 0.7978845608028654f * (val + 0.044715f * val * val * val);
          t2 = fminf(fmaxf(t2, -15.f), 15.f);
          float e2 = __expf(2.f * t2);
          float th = 1.f - 2.f / (e2 + 1.f);
          ((u16*)outp)[(long)row * ldc + col] = f2b(0.5f * val * (1.f + th));
        } else if (MODE == 6) {
          float* o = (float*)outp;
          long idx = (long)row * 1152 + col;
          atomicAdd(&o[idx], ada[(row >> 10) * 6912 + gofs + col] * val);
        }
      }
    }
  }
}

// ---------- host ----------
extern "C" void kernel_launch(void* const* d_in, const int* in_sizes, int n_in,
                              void* d_out, int out_size, void* d_ws, size_t ws_size,
                              hipStream_t stream) {
  const float* x    = (const float*)d_in[0];
  const float* c    = (const float*)d_in[1];
  const float* Wqkv = (const float*)d_in[2];
  const float* bqkv = (const float*)d_in[3];
  const float* Wprj = (const float*)d_in[4];
  const float* bprj = (const float*)d_in[5];
  const float* Wfc1 = (const float*)d_in[6];
  const float* bfc1 = (const float*)d_in[7];
  const float* Wfc2 = (const float*)d_in[8];
  const float* bfc2 = (const float*)d_in[9];
  const float* Wada = (const float*)d_in[10];
  const float* bada = (const float*)d_in[11];

  char* ws = (char*)d_ws;
  size_t o = 0;
  auto alloc = [&](size_t bytes) -> char* {
    char* p = ws + o;
    o += (bytes + 255) & ~(size_t)255;
    return p;
  };
  u16* wqkvT = (u16*)alloc(3456ull * 1152 * 2);
  u16* wprjT = (u16*)alloc(1152ull * 1152 * 2);
  u16* wfc1T = (u16*)alloc(4608ull * 1152 * 2);
  u16* wfc2T = (u16*)alloc(1152ull * 4608 * 2);
  float* adab = (float*)alloc(8ull * 6912 * 4);
  u16* hbuf = (u16*)alloc(8192ull * 1152 * 2);
  u16* Qb   = (u16*)alloc(25165824);           // [128][1024][96] bf16
  u16* Kb   = (u16*)alloc(25165824);
  u16* Vt   = (u16*)alloc(25165824);           // [128][96][1024]
  u16* attn = (u16*)alloc(8192ull * 1152 * 2);
  float* x2 = (float*)alloc(8192ull * 1152 * 4);
  u16* Vb = (u16*)x2;                          // V [bh][1024][96]; dead before x2 written
  u16* hmid = Qb;                              // fc1 out aliases Qb/Kb/Vt (75.5 MB), attn done

  // weights -> bf16 transposed
  wt_bf16<<<dim3(108, 36), 256, 0, stream>>>(Wqkv, wqkvT, 1152, 3456);
  wt_bf16<<<dim3(36, 36), 256, 0, stream>>>(Wprj, wprjT, 1152, 1152);
  wt_bf16<<<dim3(144, 36), 256, 0, stream>>>(Wfc1, wfc1T, 1152, 4608);
  wt_bf16<<<dim3(36, 144), 256, 0, stream>>>(Wfc2, wfc2T, 4608, 1152);
  // adaLN vectors
  ada_gemm<<<108, 512, 0, stream>>>(c, Wada, bada, adab);
  // zero Q,K pads (cols 72..95 feed the QK^T contraction) and V pads
  hipMemsetAsync(Qb, 0, 2ull * 25165824, stream);
  hipMemsetAsync(Vb, 0, 25165824, stream);
  // LN1 + modulate(shift_msa, scale_msa)
  ln_mod<<<8192, 256, 0, stream>>>(x, adab, 0, 1152, hbuf);
  // QKV projection + scatter
  gemm_bt<4, 4, 1><<<dim3(64, 27), 256, 0, stream>>>(
      hbuf, wqkvT, 1152, 0, 1, bqkv, nullptr, nullptr, nullptr, 0, Qb, Kb, Vb);
  transpose_v<<<dim3(3, 32, 128), 256, 0, stream>>>(Vb, Vt);
  // fused attention -> attn bf16 (XCD-swizzled 1D grid)
  flash_attn<<<dim3(1024), 256, 0, stream>>>(Qb, Kb, Vt, attn);
  // proj + residual + gate_msa -> x2 (fp32)
  gemm_bt<2, 4, 3><<<dim3(128, 9), 256, 0, stream>>>(
      attn, wprjT, 1152, 1152, 1, bprj, x2, x, adab, 2304, nullptr, nullptr, nullptr);
  // LN2 + modulate(shift_mlp, scale_mlp)
  ln_mod<<<8192, 256, 0, stream>>>(x2, adab, 3456, 4608, hbuf);
  // fc1 + gelu
  gemm_bt<4, 4, 4><<<dim3(64, 36), 256, 0, stream>>>(
      hbuf, wfc1T, 1152, 4608, 1, bfc1, hmid, nullptr, nullptr, 0, nullptr, nullptr, nullptr);
  // fc2: d_out = res + gate*bias, then split-K=2 blocks atomicAdd gate*partial
  out_init<<<8192, 256, 0, stream>>>(x2, adab, bfc2, (float*)d_out);
  gemm_bt<4, 4, 6><<<dim3(64, 9, 2), 256, 0, stream>>>(
      hmid, wfc2T, 4608, 1152, 2, nullptr, d_out, nullptr, adab, 5760,
      nullptr, nullptr, nullptr);
}